// Round 1
// baseline (21625.934 us; speedup 1.0000x reference)
//
#include <hip/hip_runtime.h>

#define NWG 128
#define TSTEPS 512

typedef __attribute__((ext_vector_type(8))) short short8;
typedef __attribute__((ext_vector_type(4))) float f32x4;

// ---- LDS offsets (bytes) ----
#define T0_OFF   0            // [z8|r8] rows, K=1536, 48 ksteps * 1KB = 48 KB
#define T1_OFF   49152        // [o8|c8] rows, K=1536 (c zero for k>=512), 48 KB
#define T2_OFF   98304        // [c8|0] rows, rc-range K=1024, 32 ksteps = 32 KB
#define RED_OFF  131072       // 4 KB reduction buffer
#define ZBUF_OFF 135168       // [8][64] f32
#define OBUF_OFF 137216
#define XCB_OFF  139264
#define CST_OFF  141312
#define RCS_OFF  143360
#define HST_OFF  145408
#define BIAS_OFF 147456       // [32] f32
#define LDS_BYTES 147584

__device__ inline unsigned short f2bf(float f) {
  unsigned int b = __float_as_uint(f);
  return (unsigned short)((b + 0x7FFFu + ((b >> 16) & 1u)) >> 16);  // RNE
}
__device__ inline float sigm(float x) { return 1.f / (1.f + __expf(-x)); }
__device__ inline float tanh_f(float x) { float e = __expf(2.f * x); return 1.f - 2.f / (e + 1.f); }

__global__ void __launch_bounds__(256) lmgru_kernel(
    const float* __restrict__ x,
    const float* __restrict__ Wz, const float* __restrict__ bz,
    const float* __restrict__ Wr, const float* __restrict__ br,
    const float* __restrict__ Wc, const float* __restrict__ bc,
    const float* __restrict__ Wo, const float* __restrict__ bo,
    const float* __restrict__ fcw, const float* __restrict__ fcb,
    float* __restrict__ out, char* __restrict__ ws)
{
  extern __shared__ char lds[];
  const int tid  = threadIdx.x;
  const int wg   = blockIdx.x;
  const int lane = tid & 63;
  const int q    = tid >> 6;          // wave id 0..3

  // ---- workspace layout ----
  unsigned short* hbuf  = (unsigned short*)ws;               // [2][64][1024] bf16
  unsigned short* rcbuf = (unsigned short*)(ws + 262144);    // [2][64][1024] bf16
  unsigned short* xring = (unsigned short*)(ws + 524288);    // [2][64][512]  bf16
  float*          h32   = (float*)(ws + 655360);             // [64][1024] f32
  int* hflagA  = (int*)(ws + 917504);
  int* hflagB  = hflagA + 128;
  int* rcflagA = hflagA + 256;
  int* rcflagB = hflagA + 384;
  int* hflag[2]  = {hflagA, hflagB};
  int* rcflag[2] = {rcflagA, rcflagB};

  float* zbuf = (float*)(lds + ZBUF_OFF);
  float* obuf = (float*)(lds + OBUF_OFF);
  float* xcb  = (float*)(lds + XCB_OFF);
  float* cst  = (float*)(lds + CST_OFF);
  float* rcs  = (float*)(lds + RCS_OFF);
  float* hst  = (float*)(lds + HST_OFF);
  float* bias = (float*)(lds + BIAS_OFF);

  const float* Wg[4] = {Wz, Wr, Wo, Wc};   // n-row layout: [z8 r8 o8 c8]

  // ================= INIT: build fragment-ordered bf16 weights in LDS =================
  // T0: rows [z8|r8], full K=1536 (48 ksteps). B-frag: n=lane&15, k=32s+(lane>>4)*8+j
  for (int it = 0; it < 12; ++it) {
    int slot = tid + 256 * it;               // 3072 slots
    int s = slot >> 6, l = slot & 63;
    int nn = l & 15, kg = (l >> 4) & 3;
    int k = 32 * s + kg * 8;
    int g = (nn < 8) ? 0 : 1;
    const float* src = Wg[g] + (8 * wg + (nn & 7)) * 1536 + k;
    short8 pk;
    #pragma unroll
    for (int j = 0; j < 8; ++j) pk[j] = (short)f2bf(src[j]);
    *(short8*)(lds + T0_OFF + s * 1024 + l * 16) = pk;
  }
  // T1: rows [o8|c8]; c rows zero for k>=512 (h-range excluded for c)
  for (int it = 0; it < 12; ++it) {
    int slot = tid + 256 * it;
    int s = slot >> 6, l = slot & 63;
    int nn = l & 15, kg = (l >> 4) & 3;
    int k = 32 * s + kg * 8;
    int g = (nn < 8) ? 2 : 3;
    short8 pk = {};
    if (g == 2 || k < 512) {
      const float* src = Wg[g] + (8 * wg + (nn & 7)) * 1536 + k;
      #pragma unroll
      for (int j = 0; j < 8; ++j) pk[j] = (short)f2bf(src[j]);
    }
    *(short8*)(lds + T1_OFF + s * 1024 + l * 16) = pk;
  }
  // T2: rows [c8|0], rc-range = weight cols [512,1536), 32 ksteps
  for (int it = 0; it < 8; ++it) {
    int slot = tid + 256 * it;               // 2048 slots
    int s = slot >> 6, l = slot & 63;
    int nn = l & 15, kg = (l >> 4) & 3;
    int k = 32 * s + kg * 8;                 // 0..1023
    short8 pk = {};
    if (nn < 8) {
      const float* src = Wc + (8 * wg + nn) * 1536 + 512 + k;
      #pragma unroll
      for (int j = 0; j < 8; ++j) pk[j] = (short)f2bf(src[j]);
    }
    *(short8*)(lds + T2_OFF + s * 1024 + l * 16) = pk;
  }
  if (tid < 32) {
    const float* Bg[4] = {bz, br, bo, bc};
    bias[tid] = Bg[tid >> 3][8 * wg + (tid & 7)];
  }
  cst[tid] = 0.f; cst[tid + 256] = 0.f;      // c state = 0
  if (tid < 64) {                            // h_0 = 0 (parity 0, own 8 units, all 64 batches)
    short8 z8 = {};
    *(short8*)(hbuf + tid * 1024 + 8 * wg) = z8;
  }
  {                                          // x for step 1 -> xring parity 1
    int idx = wg * 256 + tid; int b = idx >> 9, f = idx & 511;
    xring[32768 + b * 512 + f] = f2bf(x[b * 262144 + f]);
  }
  __syncthreads();
  if (tid == 0) {                            // flags: poison(negative) -> 0 releases init
    __hip_atomic_store(&hflagA[wg], 0, __ATOMIC_RELEASE, __HIP_MEMORY_SCOPE_AGENT);
    __hip_atomic_store(&hflagB[wg], 0, __ATOMIC_RELEASE, __HIP_MEMORY_SCOPE_AGENT);
    __hip_atomic_store(&rcflagA[wg], 0, __ATOMIC_RELEASE, __HIP_MEMORY_SCOPE_AGENT);
    __hip_atomic_store(&rcflagB[wg], 0, __ATOMIC_RELEASE, __HIP_MEMORY_SCOPE_AGENT);
  }

  const int m   = q & 1;                 // M-tile (16 batches within half)
  const int kh  = q >> 1;                // K-half
  const int nn  = lane & 15;             // fragment col / A row
  const int kg8 = ((lane >> 4) & 3) * 8; // A-frag k offset within kstep
  const int rbase = ((lane >> 4) & 3) * 4;

  // ================= RECURRENCE =================
  for (int t = 1; t <= TSTEPS; ++t) {
    const int pc = t & 1, pp = (t - 1) & 1;

    // ---------- PHASE 1 (z, r, o preacts + Xc), halves A then B ----------
    for (int X = 0; X < 2; ++X) {
      if (tid < 128) {
        while (__hip_atomic_load(&hflag[X][tid], __ATOMIC_RELAXED, __HIP_MEMORY_SCOPE_AGENT) < t - 1)
          __builtin_amdgcn_s_sleep(2);
      }
      __syncthreads();
      __builtin_amdgcn_fence(__ATOMIC_ACQUIRE, "agent");

      const int bbase = 32 * X;
      const int brow  = bbase + 16 * m + nn;
      f32x4 acc0 = {0.f, 0.f, 0.f, 0.f}, acc1 = {0.f, 0.f, 0.f, 0.f};
      const unsigned short* xr = xring + pc * 32768 + brow * 512;
      const unsigned short* hb = hbuf + pp * 65536 + brow * 1024;
      for (int s = 24 * kh; s < 24 * kh + 24; ++s) {
        int k = 32 * s + kg8;
        short8 a = (k < 512) ? *(const short8*)(xr + k)
                             : *(const short8*)(hb + (k - 512));
        short8 b0 = *(const short8*)(lds + T0_OFF + s * 1024 + lane * 16);
        short8 b1 = *(const short8*)(lds + T1_OFF + s * 1024 + lane * 16);
        acc0 = __builtin_amdgcn_mfma_f32_16x16x32_bf16(a, b0, acc0, 0, 0, 0);
        acc1 = __builtin_amdgcn_mfma_f32_16x16x32_bf16(a, b1, acc1, 0, 0, 0);
      }
      if (kh == 1) {
        *(f32x4*)(lds + RED_OFF + ((m * 2 + 0) * 64 + lane) * 16) = acc0;
        *(f32x4*)(lds + RED_OFF + ((m * 2 + 1) * 64 + lane) * 16) = acc1;
      }
      __syncthreads();
      if (kh == 0) {
        acc0 += *(const f32x4*)(lds + RED_OFF + ((m * 2 + 0) * 64 + lane) * 16);
        acc1 += *(const f32x4*)(lds + RED_OFF + ((m * 2 + 1) * 64 + lane) * 16);
        #pragma unroll
        for (int i = 0; i < 4; ++i) {
          int b = bbase + 16 * m + rbase + i;
          float v0 = acc0[i] + bias[nn];        // z or r preact
          float v1 = acc1[i] + bias[16 + nn];   // o preact or Xc(+bias_c)
          if (nn < 8) {
            zbuf[nn * 64 + b] = sigm(v0);
            obuf[nn * 64 + b] = sigm(v1);
          } else {
            int u = nn - 8;
            rcs[u * 64 + b] = sigm(v0) * cst[u * 64 + b];  // r * c_{t-1}
            xcb[u * 64 + b] = v1;                           // Xc + bias_c
          }
        }
      }
      __syncthreads();
      if (tid < 32) {                            // pack rc slice -> global (16B store)
        int b = bbase + tid;
        short8 pk;
        #pragma unroll
        for (int u = 0; u < 8; ++u) pk[u] = (short)f2bf(rcs[u * 64 + b]);
        *(short8*)(rcbuf + pc * 65536 + b * 1024 + 8 * wg) = pk;
      }
      __syncthreads();
      if (tid == 0)
        __hip_atomic_store(&rcflag[X][wg], t, __ATOMIC_RELEASE, __HIP_MEMORY_SCOPE_AGENT);
    }

    // ---------- PHASE 2 (c_tilde, combine, publish h), halves A then B ----------
    for (int X = 0; X < 2; ++X) {
      if (tid < 128) {
        while (__hip_atomic_load(&rcflag[X][tid], __ATOMIC_RELAXED, __HIP_MEMORY_SCOPE_AGENT) < t)
          __builtin_amdgcn_s_sleep(2);
      }
      __syncthreads();
      __builtin_amdgcn_fence(__ATOMIC_ACQUIRE, "agent");

      const int bbase = 32 * X;
      const int brow  = bbase + 16 * m + nn;
      f32x4 acc = {0.f, 0.f, 0.f, 0.f};
      const unsigned short* rb = rcbuf + pc * 65536 + brow * 1024;
      for (int s = 16 * kh; s < 16 * kh + 16; ++s) {
        int k = 32 * s + kg8;
        short8 a  = *(const short8*)(rb + k);
        short8 bf = *(const short8*)(lds + T2_OFF + s * 1024 + lane * 16);
        acc = __builtin_amdgcn_mfma_f32_16x16x32_bf16(a, bf, acc, 0, 0, 0);
      }
      if (kh == 1) *(f32x4*)(lds + RED_OFF + (m * 64 + lane) * 16) = acc;
      __syncthreads();
      if (kh == 0 && nn < 8) {
        acc += *(const f32x4*)(lds + RED_OFF + (m * 64 + lane) * 16);
        #pragma unroll
        for (int i = 0; i < 4; ++i) {
          int b = bbase + 16 * m + rbase + i;
          float ct = tanh_f(acc[i] + xcb[nn * 64 + b]);
          float z  = zbuf[nn * 64 + b];
          float cn = z * cst[nn * 64 + b] + (1.f - z) * ct;
          cst[nn * 64 + b] = cn;
          hst[nn * 64 + b] = obuf[nn * 64 + b] * tanh_f(cn);
        }
      }
      __syncthreads();
      if (tid < 32) {
        int b = bbase + tid;
        if (t < TSTEPS) {
          short8 pk;
          #pragma unroll
          for (int u = 0; u < 8; ++u) pk[u] = (short)f2bf(hst[u * 64 + b]);
          *(short8*)(hbuf + pc * 65536 + b * 1024 + 8 * wg) = pk;
        } else {
          #pragma unroll
          for (int u = 0; u < 8; ++u) h32[b * 1024 + 8 * wg + u] = hst[u * 64 + b];
        }
      }
      if (X == 0 && t < TSTEPS) {                // convert x for step t+1 (before hA publish)
        int idx = wg * 256 + tid; int b = idx >> 9, f = idx & 511;
        xring[((t + 1) & 1) * 32768 + b * 512 + f] = f2bf(x[b * 262144 + t * 512 + f]);
      }
      __syncthreads();
      if (tid == 0)
        __hip_atomic_store(&hflag[X][wg], t, __ATOMIC_RELEASE, __HIP_MEMORY_SCOPE_AGENT);
    }
  }

  // ================= FINAL FC: out = h_T @ fc_w^T + fc_b =================
  if (tid < 128) {
    while (__hip_atomic_load(&hflagA[tid], __ATOMIC_RELAXED, __HIP_MEMORY_SCOPE_AGENT) < TSTEPS)
      __builtin_amdgcn_s_sleep(2);
    while (__hip_atomic_load(&hflagB[tid], __ATOMIC_RELAXED, __HIP_MEMORY_SCOPE_AGENT) < TSTEPS)
      __builtin_amdgcn_s_sleep(2);
  }
  __syncthreads();
  __builtin_amdgcn_fence(__ATOMIC_ACQUIRE, "agent");

  if (wg < 125) {                                // 125 WGs * 8 classes = 1000
    for (int cc = 0; cc < 2; ++cc) {
      int c = 8 * wg + 2 * q + cc;
      const float* wrow = fcw + c * 1024;
      for (int b = 0; b < 64; ++b) {
        const float* hrow = h32 + b * 1024;
        float s = 0.f;
        for (int kk = lane; kk < 1024; kk += 64) s = __builtin_fmaf(hrow[kk], wrow[kk], s);
        #pragma unroll
        for (int off = 32; off; off >>= 1) s += __shfl_xor(s, off);
        if (lane == 0) out[b * 1000 + c] = s + fcb[c];
      }
    }
  }
}

extern "C" void kernel_launch(void* const* d_in, const int* in_sizes, int n_in,
                              void* d_out, int out_size, void* d_ws, size_t ws_size,
                              hipStream_t stream) {
  (void)in_sizes; (void)n_in; (void)out_size; (void)ws_size;
  const float* x   = (const float*)d_in[0];
  const float* Wz  = (const float*)d_in[1];
  const float* bz  = (const float*)d_in[2];
  const float* Wr  = (const float*)d_in[3];
  const float* br  = (const float*)d_in[4];
  const float* Wc  = (const float*)d_in[5];
  const float* bc  = (const float*)d_in[6];
  const float* Wo  = (const float*)d_in[7];
  const float* bo  = (const float*)d_in[8];
  const float* fcw = (const float*)d_in[9];
  const float* fcb = (const float*)d_in[10];

  hipFuncSetAttribute((const void*)lmgru_kernel,
                      hipFuncAttributeMaxDynamicSharedMemorySize, LDS_BYTES);

  hipLaunchKernelGGL(lmgru_kernel, dim3(NWG), dim3(256), LDS_BYTES, stream,
                     x, Wz, bz, Wr, br, Wc, bc, Wo, bo, fcw, fcb,
                     (float*)d_out, (char*)d_ws);
}

// Round 4
// 9916.374 us; speedup vs baseline: 2.1808x; 2.1808x over previous
//
#include <hip/hip_runtime.h>

#define NWG 128
#define TSTEPS 512

typedef __attribute__((ext_vector_type(8))) short short8;
typedef __attribute__((ext_vector_type(4))) float f32x4;

// ---- LDS offsets (bytes) ----
#define T0_OFF   0            // [z8|r8] rows, K=1536, 48 ksteps * 1KB = 48 KB
#define T1_OFF   49152        // [o8|c8] rows, K=1536 (c zero for k>=512), 48 KB
#define T2_OFF   98304        // [c8|0] rows, rc-range K=1024, 32 ksteps = 32 KB
#define RED_OFF  131072       // 4 KB reduction buffer
#define ZBUF_OFF 135168       // [8][64] f32
#define OBUF_OFF 137216
#define XCB_OFF  139264
#define CST_OFF  141312
#define RCS_OFF  143360
#define HST_OFF  145408
#define BIAS_OFF 147456       // [32] f32
#define LDS_BYTES 147584

__device__ inline unsigned short f2bf(float f) {
  unsigned int b = __float_as_uint(f);
  return (unsigned short)((b + 0x7FFFu + ((b >> 16) & 1u)) >> 16);  // RNE
}
__device__ inline float sigm(float x) { return 1.f / (1.f + __expf(-x)); }
__device__ inline float tanh_f(float x) { float e = __expf(2.f * x); return 1.f - 2.f / (e + 1.f); }

// ---- fine-grained coherent (LLC-level) access helpers: no wbl2 / no inv ----
__device__ inline void cstore16(void* p, short8 v) {
  asm volatile("global_store_dwordx4 %0, %1, off sc0 sc1" :: "v"(p), "v"(v) : "memory");
}
__device__ inline void cstore4(void* p, int v) {
  asm volatile("global_store_dword %0, %1, off sc0 sc1" :: "v"(p), "v"(v) : "memory");
}
__device__ inline int cload4(const void* p) {
  int v;
  asm volatile("global_load_dword %0, %1, off sc0 sc1\n\ts_waitcnt vmcnt(0)"
               : "=&v"(v) : "v"(p) : "memory");
  return v;
}
__device__ inline void vmdrain() {
  asm volatile("s_waitcnt vmcnt(0)" ::: "memory");
}

// 24 coherent 16B loads (16 from p0 stride 64B, 8 from p1 stride 64B), one wait.
// NOTE: outputs MUST be early-clobber (=&v): the block writes outputs while still
// reading the pointer inputs on later loads; without & the allocator may alias them.
__device__ inline void cload24(const unsigned short* p0, const unsigned short* p1, short8* a) {
  asm volatile(
    "global_load_dwordx4 %0,  %24, off sc0 sc1\n\t"
    "global_load_dwordx4 %1,  %24, off offset:64 sc0 sc1\n\t"
    "global_load_dwordx4 %2,  %24, off offset:128 sc0 sc1\n\t"
    "global_load_dwordx4 %3,  %24, off offset:192 sc0 sc1\n\t"
    "global_load_dwordx4 %4,  %24, off offset:256 sc0 sc1\n\t"
    "global_load_dwordx4 %5,  %24, off offset:320 sc0 sc1\n\t"
    "global_load_dwordx4 %6,  %24, off offset:384 sc0 sc1\n\t"
    "global_load_dwordx4 %7,  %24, off offset:448 sc0 sc1\n\t"
    "global_load_dwordx4 %8,  %24, off offset:512 sc0 sc1\n\t"
    "global_load_dwordx4 %9,  %24, off offset:576 sc0 sc1\n\t"
    "global_load_dwordx4 %10, %24, off offset:640 sc0 sc1\n\t"
    "global_load_dwordx4 %11, %24, off offset:704 sc0 sc1\n\t"
    "global_load_dwordx4 %12, %24, off offset:768 sc0 sc1\n\t"
    "global_load_dwordx4 %13, %24, off offset:832 sc0 sc1\n\t"
    "global_load_dwordx4 %14, %24, off offset:896 sc0 sc1\n\t"
    "global_load_dwordx4 %15, %24, off offset:960 sc0 sc1\n\t"
    "global_load_dwordx4 %16, %25, off sc0 sc1\n\t"
    "global_load_dwordx4 %17, %25, off offset:64 sc0 sc1\n\t"
    "global_load_dwordx4 %18, %25, off offset:128 sc0 sc1\n\t"
    "global_load_dwordx4 %19, %25, off offset:192 sc0 sc1\n\t"
    "global_load_dwordx4 %20, %25, off offset:256 sc0 sc1\n\t"
    "global_load_dwordx4 %21, %25, off offset:320 sc0 sc1\n\t"
    "global_load_dwordx4 %22, %25, off offset:384 sc0 sc1\n\t"
    "global_load_dwordx4 %23, %25, off offset:448 sc0 sc1\n\t"
    "s_waitcnt vmcnt(0)"
    : "=&v"(a[0]), "=&v"(a[1]), "=&v"(a[2]), "=&v"(a[3]),
      "=&v"(a[4]), "=&v"(a[5]), "=&v"(a[6]), "=&v"(a[7]),
      "=&v"(a[8]), "=&v"(a[9]), "=&v"(a[10]), "=&v"(a[11]),
      "=&v"(a[12]), "=&v"(a[13]), "=&v"(a[14]), "=&v"(a[15]),
      "=&v"(a[16]), "=&v"(a[17]), "=&v"(a[18]), "=&v"(a[19]),
      "=&v"(a[20]), "=&v"(a[21]), "=&v"(a[22]), "=&v"(a[23])
    : "v"(p0), "v"(p1)
    : "memory");
}

// 16 coherent 16B loads from one base, stride 64B, one wait.
__device__ inline void cload16(const unsigned short* p, short8* a) {
  asm volatile(
    "global_load_dwordx4 %0,  %16, off sc0 sc1\n\t"
    "global_load_dwordx4 %1,  %16, off offset:64 sc0 sc1\n\t"
    "global_load_dwordx4 %2,  %16, off offset:128 sc0 sc1\n\t"
    "global_load_dwordx4 %3,  %16, off offset:192 sc0 sc1\n\t"
    "global_load_dwordx4 %4,  %16, off offset:256 sc0 sc1\n\t"
    "global_load_dwordx4 %5,  %16, off offset:320 sc0 sc1\n\t"
    "global_load_dwordx4 %6,  %16, off offset:384 sc0 sc1\n\t"
    "global_load_dwordx4 %7,  %16, off offset:448 sc0 sc1\n\t"
    "global_load_dwordx4 %8,  %16, off offset:512 sc0 sc1\n\t"
    "global_load_dwordx4 %9,  %16, off offset:576 sc0 sc1\n\t"
    "global_load_dwordx4 %10, %16, off offset:640 sc0 sc1\n\t"
    "global_load_dwordx4 %11, %16, off offset:704 sc0 sc1\n\t"
    "global_load_dwordx4 %12, %16, off offset:768 sc0 sc1\n\t"
    "global_load_dwordx4 %13, %16, off offset:832 sc0 sc1\n\t"
    "global_load_dwordx4 %14, %16, off offset:896 sc0 sc1\n\t"
    "global_load_dwordx4 %15, %16, off offset:960 sc0 sc1\n\t"
    "s_waitcnt vmcnt(0)"
    : "=&v"(a[0]), "=&v"(a[1]), "=&v"(a[2]), "=&v"(a[3]),
      "=&v"(a[4]), "=&v"(a[5]), "=&v"(a[6]), "=&v"(a[7]),
      "=&v"(a[8]), "=&v"(a[9]), "=&v"(a[10]), "=&v"(a[11]),
      "=&v"(a[12]), "=&v"(a[13]), "=&v"(a[14]), "=&v"(a[15])
    : "v"(p)
    : "memory");
}

__global__ void __launch_bounds__(256) lmgru_kernel(
    const float* __restrict__ x,
    const float* __restrict__ Wz, const float* __restrict__ bz,
    const float* __restrict__ Wr, const float* __restrict__ br,
    const float* __restrict__ Wc, const float* __restrict__ bc,
    const float* __restrict__ Wo, const float* __restrict__ bo,
    const float* __restrict__ fcw, const float* __restrict__ fcb,
    float* __restrict__ out, char* __restrict__ ws)
{
  extern __shared__ char lds[];
  const int tid  = threadIdx.x;
  const int wg   = blockIdx.x;
  const int lane = tid & 63;
  const int q    = tid >> 6;          // wave id 0..3

  // ---- workspace layout ----
  unsigned short* hbuf  = (unsigned short*)ws;               // [2][64][1024] bf16
  unsigned short* rcbuf = (unsigned short*)(ws + 262144);    // [2][64][1024] bf16
  unsigned short* xring = (unsigned short*)(ws + 524288);    // [2][64][512]  bf16
  float*          h32   = (float*)(ws + 655360);             // [64][1024] f32
  int* hflagA  = (int*)(ws + 917504);
  int* hflagB  = hflagA + 128;
  int* rcflagA = hflagA + 256;
  int* rcflagB = hflagA + 384;
  int* hflag[2]  = {hflagA, hflagB};
  int* rcflag[2] = {rcflagA, rcflagB};

  float* zbuf = (float*)(lds + ZBUF_OFF);
  float* obuf = (float*)(lds + OBUF_OFF);
  float* xcb  = (float*)(lds + XCB_OFF);
  float* cst  = (float*)(lds + CST_OFF);
  float* rcs  = (float*)(lds + RCS_OFF);
  float* hst  = (float*)(lds + HST_OFF);
  float* bias = (float*)(lds + BIAS_OFF);

  const float* Wg[4] = {Wz, Wr, Wo, Wc};   // n-row layout: [z8 r8 o8 c8]

  // ================= INIT: build fragment-ordered bf16 weights in LDS =================
  for (int it = 0; it < 12; ++it) {
    int slot = tid + 256 * it;               // 3072 slots
    int s = slot >> 6, l = slot & 63;
    int nn = l & 15, kg = (l >> 4) & 3;
    int k = 32 * s + kg * 8;
    int g = (nn < 8) ? 0 : 1;
    const float* src = Wg[g] + (8 * wg + (nn & 7)) * 1536 + k;
    short8 pk;
    #pragma unroll
    for (int j = 0; j < 8; ++j) pk[j] = (short)f2bf(src[j]);
    *(short8*)(lds + T0_OFF + s * 1024 + l * 16) = pk;
  }
  for (int it = 0; it < 12; ++it) {
    int slot = tid + 256 * it;
    int s = slot >> 6, l = slot & 63;
    int nn = l & 15, kg = (l >> 4) & 3;
    int k = 32 * s + kg * 8;
    int g = (nn < 8) ? 2 : 3;
    short8 pk = {};
    if (g == 2 || k < 512) {
      const float* src = Wg[g] + (8 * wg + (nn & 7)) * 1536 + k;
      #pragma unroll
      for (int j = 0; j < 8; ++j) pk[j] = (short)f2bf(src[j]);
    }
    *(short8*)(lds + T1_OFF + s * 1024 + l * 16) = pk;
  }
  for (int it = 0; it < 8; ++it) {
    int slot = tid + 256 * it;               // 2048 slots
    int s = slot >> 6, l = slot & 63;
    int nn = l & 15, kg = (l >> 4) & 3;
    int k = 32 * s + kg * 8;                 // 0..1023
    short8 pk = {};
    if (nn < 8) {
      const float* src = Wc + (8 * wg + nn) * 1536 + 512 + k;
      #pragma unroll
      for (int j = 0; j < 8; ++j) pk[j] = (short)f2bf(src[j]);
    }
    *(short8*)(lds + T2_OFF + s * 1024 + l * 16) = pk;
  }
  if (tid < 32) {
    const float* Bg[4] = {bz, br, bo, bc};
    bias[tid] = Bg[tid >> 3][8 * wg + (tid & 7)];
  }
  cst[tid] = 0.f; cst[tid + 256] = 0.f;      // c state = 0
  if (tid < 64) {                            // h_0 = 0 (parity 0) -- coherent
    short8 z8 = {};
    cstore16(hbuf + tid * 1024 + 8 * wg, z8);
  }
  if (tid < 32) {                            // x for step 1 -> xring parity 1 (coherent)
    int e = wg * 256 + tid * 8;
    int b = e >> 9, f = e & 511;
    const float* xs = x + b * 262144 + f;
    short8 pk;
    #pragma unroll
    for (int j = 0; j < 8; ++j) pk[j] = (short)f2bf(xs[j]);
    cstore16(xring + 32768 + b * 512 + f, pk);
  }
  __syncthreads();
  if (tid == 0) {                            // flags: poison(negative) -> 0 releases init
    vmdrain();
    cstore4(&hflagA[wg], 0);
    cstore4(&hflagB[wg], 0);
    cstore4(&rcflagA[wg], 0);
    cstore4(&rcflagB[wg], 0);
  }

  const int m   = q & 1;                 // M-tile (16 batches within half)
  const int kh  = q >> 1;                // K-half
  const int nn  = lane & 15;             // fragment col / A row
  const int kg8 = ((lane >> 4) & 3) * 8; // A-frag k offset within kstep
  const int rbase = ((lane >> 4) & 3) * 4;

  // ================= RECURRENCE =================
  for (int t = 1; t <= TSTEPS; ++t) {
    const int pc = t & 1, pp = (t - 1) & 1;

    // ---------- PHASE 1 (z, r, o preacts + Xc), halves A then B ----------
    for (int X = 0; X < 2; ++X) {
      if (tid < 128) {
        const int* fp = &hflag[X][tid];
        while (cload4(fp) < t - 1) __builtin_amdgcn_s_sleep(1);
      }
      __syncthreads();

      const int bbase = 32 * X;
      const int brow  = bbase + 16 * m + nn;
      f32x4 acc0 = {0.f, 0.f, 0.f, 0.f}, acc1 = {0.f, 0.f, 0.f, 0.f};
      const unsigned short* xr = xring + pc * 32768 + brow * 512;
      const unsigned short* hb = hbuf + pp * 65536 + brow * 1024;
      const unsigned short* p0 = kh ? (hb + 256 + kg8) : (xr + kg8);
      const unsigned short* p1 = kh ? (hb + 768 + kg8) : (hb + kg8);
      short8 af[24];
      cload24(p0, p1, af);
      #pragma unroll
      for (int j = 0; j < 24; ++j) {
        int s = 24 * kh + j;
        short8 b0 = *(const short8*)(lds + T0_OFF + s * 1024 + lane * 16);
        short8 b1 = *(const short8*)(lds + T1_OFF + s * 1024 + lane * 16);
        acc0 = __builtin_amdgcn_mfma_f32_16x16x32_bf16(af[j], b0, acc0, 0, 0, 0);
        acc1 = __builtin_amdgcn_mfma_f32_16x16x32_bf16(af[j], b1, acc1, 0, 0, 0);
      }
      if (kh == 1) {
        *(f32x4*)(lds + RED_OFF + ((m * 2 + 0) * 64 + lane) * 16) = acc0;
        *(f32x4*)(lds + RED_OFF + ((m * 2 + 1) * 64 + lane) * 16) = acc1;
      }
      __syncthreads();
      if (kh == 0) {
        acc0 += *(const f32x4*)(lds + RED_OFF + ((m * 2 + 0) * 64 + lane) * 16);
        acc1 += *(const f32x4*)(lds + RED_OFF + ((m * 2 + 1) * 64 + lane) * 16);
        #pragma unroll
        for (int i = 0; i < 4; ++i) {
          int b = bbase + 16 * m + rbase + i;
          float v0 = acc0[i] + bias[nn];        // z or r preact
          float v1 = acc1[i] + bias[16 + nn];   // o preact or Xc(+bias_c)
          if (nn < 8) {
            zbuf[nn * 64 + b] = sigm(v0);
            obuf[nn * 64 + b] = sigm(v1);
          } else {
            int u = nn - 8;
            rcs[u * 64 + b] = sigm(v0) * cst[u * 64 + b];  // r * c_{t-1}
            xcb[u * 64 + b] = v1;                           // Xc + bias_c
          }
        }
      }
      __syncthreads();
      if (tid < 32) {                            // pack rc slice -> global (coherent 16B)
        int b = bbase + tid;
        short8 pk;
        #pragma unroll
        for (int u = 0; u < 8; ++u) pk[u] = (short)f2bf(rcs[u * 64 + b]);
        cstore16(rcbuf + pc * 65536 + b * 1024 + 8 * wg, pk);
      }
      if (tid == 0) {                            // data stores all in wave 0 -> vmcnt orders
        vmdrain();
        cstore4(&rcflag[X][wg], t);
      }
    }

    // ---------- PHASE 2 (c_tilde, combine, publish h), halves A then B ----------
    for (int X = 0; X < 2; ++X) {
      if (tid < 128) {
        const int* fp = &rcflag[X][tid];
        while (cload4(fp) < t) __builtin_amdgcn_s_sleep(1);
      }
      __syncthreads();

      const int bbase = 32 * X;
      const int brow  = bbase + 16 * m + nn;
      f32x4 acc = {0.f, 0.f, 0.f, 0.f};
      const unsigned short* rb = rcbuf + pc * 65536 + brow * 1024;
      short8 af[16];
      cload16(rb + kg8 + (kh ? 512 : 0), af);   // kh=1 half starts at element 32*16=512
      #pragma unroll
      for (int j = 0; j < 16; ++j) {
        int s = 16 * kh + j;
        short8 bf = *(const short8*)(lds + T2_OFF + s * 1024 + lane * 16);
        acc = __builtin_amdgcn_mfma_f32_16x16x32_bf16(af[j], bf, acc, 0, 0, 0);
      }
      if (kh == 1) *(f32x4*)(lds + RED_OFF + (m * 64 + lane) * 16) = acc;
      __syncthreads();
      if (kh == 0 && nn < 8) {
        acc += *(const f32x4*)(lds + RED_OFF + (m * 64 + lane) * 16);
        #pragma unroll
        for (int i = 0; i < 4; ++i) {
          int b = bbase + 16 * m + rbase + i;
          float ct = tanh_f(acc[i] + xcb[nn * 64 + b]);
          float z  = zbuf[nn * 64 + b];
          float cn = z * cst[nn * 64 + b] + (1.f - z) * ct;
          cst[nn * 64 + b] = cn;
          hst[nn * 64 + b] = obuf[nn * 64 + b] * tanh_f(cn);
        }
      }
      __syncthreads();
      if (tid < 32) {
        int b = bbase + tid;
        if (t < TSTEPS) {
          short8 pk;
          #pragma unroll
          for (int u = 0; u < 8; ++u) pk[u] = (short)f2bf(hst[u * 64 + b]);
          cstore16(hbuf + pc * 65536 + b * 1024 + 8 * wg, pk);
        } else {
          #pragma unroll
          for (int u = 0; u < 8; ++u) h32[b * 1024 + 8 * wg + u] = hst[u * 64 + b];
        }
      }
      if (X == 0 && t < TSTEPS && tid < 32) {    // convert x for step t+1 (coherent 16B)
        int e = wg * 256 + tid * 8;
        int b = e >> 9, f = e & 511;
        const float* xs = x + b * 262144 + t * 512 + f;
        short8 pk;
        #pragma unroll
        for (int j = 0; j < 8; ++j) pk[j] = (short)f2bf(xs[j]);
        cstore16(xring + ((t + 1) & 1) * 32768 + b * 512 + f, pk);
      }
      if (tid == 0) {
        if (t < TSTEPS) {
          vmdrain();
          cstore4(&hflag[X][wg], t);
        } else {
          // final handoff: h32 written with normal stores -> one wbl2 here
          __hip_atomic_store(&hflag[X][wg], t, __ATOMIC_RELEASE, __HIP_MEMORY_SCOPE_AGENT);
        }
      }
    }
  }

  // ================= FINAL FC: out = h_T @ fc_w^T + fc_b =================
  if (tid < 128) {
    while (__hip_atomic_load(&hflagA[tid], __ATOMIC_RELAXED, __HIP_MEMORY_SCOPE_AGENT) < TSTEPS)
      __builtin_amdgcn_s_sleep(1);
    while (__hip_atomic_load(&hflagB[tid], __ATOMIC_RELAXED, __HIP_MEMORY_SCOPE_AGENT) < TSTEPS)
      __builtin_amdgcn_s_sleep(1);
  }
  __syncthreads();
  __builtin_amdgcn_fence(__ATOMIC_ACQUIRE, "agent");   // one L2 inv, one-time

  if (wg < 125) {                                // 125 WGs * 8 classes = 1000
    for (int cc = 0; cc < 2; ++cc) {
      int c = 8 * wg + 2 * q + cc;
      const float* wrow = fcw + c * 1024;
      for (int b = 0; b < 64; ++b) {
        const float* hrow = h32 + b * 1024;
        float s = 0.f;
        for (int kk = lane; kk < 1024; kk += 64) s = __builtin_fmaf(hrow[kk], wrow[kk], s);
        #pragma unroll
        for (int off = 32; off; off >>= 1) s += __shfl_xor(s, off);
        if (lane == 0) out[b * 1000 + c] = s + fcb[c];
      }
    }
  }
}

extern "C" void kernel_launch(void* const* d_in, const int* in_sizes, int n_in,
                              void* d_out, int out_size, void* d_ws, size_t ws_size,
                              hipStream_t stream) {
  (void)in_sizes; (void)n_in; (void)out_size; (void)ws_size;
  const float* x   = (const float*)d_in[0];
  const float* Wz  = (const float*)d_in[1];
  const float* bz  = (const float*)d_in[2];
  const float* Wr  = (const float*)d_in[3];
  const float* br  = (const float*)d_in[4];
  const float* Wc  = (const float*)d_in[5];
  const float* bc  = (const float*)d_in[6];
  const float* Wo  = (const float*)d_in[7];
  const float* bo  = (const float*)d_in[8];
  const float* fcw = (const float*)d_in[9];
  const float* fcb = (const float*)d_in[10];

  hipFuncSetAttribute((const void*)lmgru_kernel,
                      hipFuncAttributeMaxDynamicSharedMemorySize, LDS_BYTES);

  hipLaunchKernelGGL(lmgru_kernel, dim3(NWG), dim3(256), LDS_BYTES, stream,
                     x, Wz, bz, Wr, br, Wc, bc, Wo, bo, fcw, fcb,
                     (float*)d_out, (char*)d_ws);
}